// Round 1
// baseline (458.282 us; speedup 1.0000x reference)
//
#include <hip/hip_runtime.h>
#include <math.h>

// Problem constants
#define BHN     55392          // B*H*N = 8*12*577 (token count)
#define NTOK    577
#define HD      64
#define EPS_F   1e-6f
#define TOTAL_ELEMS 31961184   // BHN * 577
#define TOTAL_VEC   7990296    // TOTAL_ELEMS / 4  (divisible: 96*577*577 % 4 == 0)

// ---------------------------------------------------------------------------
// Kernel A: per-token sigma MLP -> folded quadratic-form coefficients.
// coef[tok] = { a, b, c, pack } where w = a*dx^2 + b*dx*dy + c*dy^2
//   a = -0.5*inv00, b = -inv01 (absorbs the 2x), c = -0.5*inv11
//   pack = float(ri*32 + ci) of token's grid position; for i==0 store a=b=c=0
//   (then w==0 for the whole row, which reproduces the zero-padded dists row).
// ---------------------------------------------------------------------------
__global__ __launch_bounds__(64) void sigma_coef_kernel(
    const float* __restrict__ q,  const float* __restrict__ W1,
    const float* __restrict__ b1, const float* __restrict__ W2,
    const float* __restrict__ b2, float4* __restrict__ coef)
{
    int tok = blockIdx.x * 64 + threadIdx.x;
    if (tok >= BHN) return;

    // Load this token's query row (256B aligned -> float4)
    float qv[HD];
    const float4* q4 = (const float4*)(q + (size_t)tok * HD);
    #pragma unroll
    for (int k = 0; k < HD / 4; ++k) {
        float4 v = q4[k];
        qv[4*k+0] = v.x; qv[4*k+1] = v.y; qv[4*k+2] = v.z; qv[4*k+3] = v.w;
    }

    // h = q @ W1 + b1   (W1 is (64,64) row-major; uniform addresses -> s_loads)
    float h[HD];
    #pragma unroll
    for (int t = 0; t < HD; ++t) h[t] = b1[t];
    #pragma unroll
    for (int k = 0; k < HD; ++k) {
        float qk = qv[k];
        const float* w1row = W1 + k * HD;
        #pragma unroll
        for (int t = 0; t < HD; ++t) h[t] = fmaf(qk, w1row[t], h[t]);
    }

    // s = gelu(h) @ W2 + b2   (exact gelu: 0.5*x*(1+erf(x/sqrt(2))))
    float s0 = b2[0], s1 = b2[1], s2 = b2[2];
    #pragma unroll
    for (int t = 0; t < HD; ++t) {
        float x = h[t];
        float g = 0.5f * x * (1.0f + erff(x * 0.70710678118654752f));
        s0 = fmaf(g, W2[t*3 + 0], s0);
        s1 = fmaf(g, W2[t*3 + 1], s1);
        s2 = fmaf(g, W2[t*3 + 2], s2);
    }

    float sx  = fmaxf(s0, 0.0f) + 1.0f;
    float sy  = fmaxf(s1, 0.0f) + 1.0f;
    float rho = 0.99f * tanhf(s2);
    float sxx = sx * sx;
    float syy = sy * sy;
    float sxy = rho * sx * sy;
    float det = sxx * syy - sxy * sxy;   // >= 0.0199, safe
    float inv_det = 1.0f / det;

    float a = -0.5f * syy * inv_det;     // -0.5*inv00
    float b =  sxy * inv_det;            // -inv01 (coefficient of dx*dy in w)
    float c = -0.5f * sxx * inv_det;     // -0.5*inv11

    int i = tok % NTOK;                  // token index within (b,h)
    float pack;
    if (i == 0) {                        // CLS row: dists padded to 0 -> w == 0
        a = 0.0f; b = 0.0f; c = 0.0f; pack = 0.0f;
    } else {
        int ip = i - 1;
        int ri = ip / 24;
        int ci = ip - ri * 24;
        pack = (float)(ri * 32 + ci);
    }
    coef[tok] = make_float4(a, b, c, pack);
}

// ---------------------------------------------------------------------------
// Kernel B: elementwise mask. rowmax(kernel)==1 always (j=0 column has w=0 and
// w<=0 since Sigma^-1 is PD), so probs = clip(exp(w), eps, 1-eps) directly.
// logits + noise folded: log(p*u) - log((1-p)*(1-u))  -> 2 logs + 2 exps.
// ---------------------------------------------------------------------------
__global__ __launch_bounds__(256) void mask_kernel(
    const float4* __restrict__ u4, const float4* __restrict__ coef,
    float4* __restrict__ out4)
{
    int vid = blockIdx.x * 256 + threadIdx.x;
    if (vid >= TOTAL_VEC) return;

    int e0 = vid * 4;                           // < 2^31, fine
    unsigned row0 = (unsigned)e0 / 577u;        // magic-div
    int j0 = e0 - (int)row0 * 577;

    float4 uu = u4[vid];
    float um[4] = {uu.x, uu.y, uu.z, uu.w};
    float res[4];

    #pragma unroll
    for (int m = 0; m < 4; ++m) {
        unsigned row = row0;
        int j = j0 + m;
        if (j >= 577) { row += 1u; j -= 577; }  // at most one row crossing

        float4 cf = coef[row];                  // L1-broadcast within wave
        int rc = (int)cf.w;

        float dx = 0.0f, dy = 0.0f;
        if (j > 0) {
            unsigned jj = (unsigned)(j - 1);
            unsigned rj = jj / 24u;             // magic-div
            unsigned cj = jj - rj * 24u;
            dx = (float)((rc >> 5) - (int)rj);
            dy = (float)((rc & 31) - (int)cj);
        }

        // w = a*dx^2 + b*dx*dy + c*dy^2  (<= 0)
        float w = fmaf(fmaf(cf.x, dx, cf.y * dy), dx, cf.z * (dy * dy));

        float p = __expf(w);
        p = fminf(fmaxf(p, EPS_F), 1.0f - EPS_F);

        float uk  = um[m];
        float num = p * uk;                      // >= 1e-12, no underflow
        float den = (1.0f - p) * (1.0f - uk);
        float t = 10.0f * (__logf(num) - __logf(den));   // (logits+noise)/TEMP

        // sigmoid(t); exp(-t) may be inf (t<-88) -> rcp(inf)=0, or 0 -> 1. Both OK.
        res[m] = __builtin_amdgcn_rcpf(1.0f + __expf(-t));
    }

    out4[vid] = make_float4(res[0], res[1], res[2], res[3]);
}

// ---------------------------------------------------------------------------
extern "C" void kernel_launch(void* const* d_in, const int* in_sizes, int n_in,
                              void* d_out, int out_size, void* d_ws, size_t ws_size,
                              hipStream_t stream) {
    const float* q  = (const float*)d_in[0];   // (8,12,577,64)
    const float* W1 = (const float*)d_in[1];   // (64,64)
    const float* b1 = (const float*)d_in[2];   // (64,)
    const float* W2 = (const float*)d_in[3];   // (64,3)
    const float* b2 = (const float*)d_in[4];   // (3,)
    const float* u  = (const float*)d_in[5];   // (8,12,577,577)
    // d_in[6] = dists: recomputed on the fly, not loaded.

    float4* coef = (float4*)d_ws;              // BHN * 16 B = 886 KB scratch

    sigma_coef_kernel<<<(BHN + 63) / 64, 64, 0, stream>>>(q, W1, b1, W2, b2, coef);
    mask_kernel<<<(TOTAL_VEC + 255) / 256, 256, 0, stream>>>(
        (const float4*)u, coef, (float4*)d_out);
}

// Round 2
// 256.286 us; speedup vs baseline: 1.7882x; 1.7882x over previous
//
#include <hip/hip_runtime.h>
#include <math.h>

// Problem constants
#define BHN     55392          // B*H*N = 8*12*577 (token count)
#define NTOK    577
#define HD      64
#define EPS_F   1e-6f
#define TOTAL_ELEMS 31961184   // BHN * 577
#define TOTAL_VEC   7990296    // TOTAL_ELEMS / 4

// ---------------------------------------------------------------------------
// Kernel A v2: per-token sigma MLP -> folded quadratic-form coefficients.
// coef[tok] = { a, b, c, pack }, w = a*dx^2 + b*dx*dy + c*dy^2.
// v2 fixes: W1 in LDS (broadcast ds_read_b128), ROLLED k-loop (small body,
// I-cache resident), 256-thd blocks for occupancy, branchless erf/tanh.
// ---------------------------------------------------------------------------
__global__ __launch_bounds__(256) void sigma_coef_kernel(
    const float* __restrict__ q,  const float* __restrict__ W1,
    const float* __restrict__ b1, const float* __restrict__ W2,
    const float* __restrict__ b2, float4* __restrict__ coef)
{
    __shared__ float w1s[64 * 64];           // 16 KB
    const int tid = threadIdx.x;

    // cooperative W1 stage: 1024 float4 / 256 threads = 4 each, coalesced
    {
        const float4* w4 = (const float4*)W1;
        float4* s4 = (float4*)w1s;
        #pragma unroll
        for (int i = 0; i < 4; ++i)
            s4[tid + 256 * i] = w4[tid + 256 * i];
    }
    __syncthreads();

    const int tok = blockIdx.x * 256 + tid;
    if (tok >= BHN) return;

    float h[HD];
    #pragma unroll
    for (int t = 0; t < HD; ++t) h[t] = 0.0f;

    // h = q @ W1  (b1 added in epilogue). Rolled kk-loop: body = 1 vload +
    // 64 broadcast ds_read_b128 + 256 v_fmac  (~3 KB code).
    const float4* q4 = (const float4*)(q + (size_t)tok * HD);
    float4 qv = q4[0];
    #pragma unroll 1
    for (int kk = 0; kk < 16; ++kk) {
        const int kn = (kk < 15) ? (kk + 1) : 15;
        float4 qnext = q4[kn];                       // prefetch next chunk
        const float4* wrow = (const float4*)(w1s + kk * 4 * HD);
        float qk[4] = {qv.x, qv.y, qv.z, qv.w};
        #pragma unroll
        for (int d = 0; d < 4; ++d) {
            float qs = qk[d];
            #pragma unroll
            for (int t4 = 0; t4 < 16; ++t4) {
                float4 wv = wrow[d * 16 + t4];
                h[4*t4+0] = fmaf(qs, wv.x, h[4*t4+0]);
                h[4*t4+1] = fmaf(qs, wv.y, h[4*t4+1]);
                h[4*t4+2] = fmaf(qs, wv.z, h[4*t4+2]);
                h[4*t4+3] = fmaf(qs, wv.w, h[4*t4+3]);
            }
        }
        qv = qnext;
    }

    // s = gelu(h + b1) @ W2 + b2.  erf via A&S 7.1.26 (|err| <= 1.5e-7),
    // branchless (~20 instrs/term vs libm erff's branchy ~60).
    float s0 = b2[0], s1 = b2[1], s2 = b2[2];
    #pragma unroll
    for (int t = 0; t < HD; ++t) {
        float x = h[t] + b1[t];
        float z = x * 0.70710678118654752f;
        float az = fabsf(z);
        float k = __builtin_amdgcn_rcpf(fmaf(0.3275911f, az, 1.0f));
        float poly = k * (0.254829592f + k * (-0.284496736f +
                     k * (1.421413741f + k * (-1.453152027f +
                     k * 1.061405429f))));
        float om = poly * __expf(-z * z);            // 1 - erf(|z|)
        float erfz = copysignf(1.0f - om, z);
        float g = 0.5f * x * (1.0f + erfz);
        s0 = fmaf(g, W2[t*3 + 0], s0);
        s1 = fmaf(g, W2[t*3 + 1], s1);
        s2 = fmaf(g, W2[t*3 + 2], s2);
    }

    float sx = fmaxf(s0, 0.0f) + 1.0f;
    float sy = fmaxf(s1, 0.0f) + 1.0f;
    // tanh(x) = (e^2x - 1)/(e^2x + 1), branchless; s2 is O(0.02) so no overflow
    float ex = __expf(2.0f * s2);
    float rho = 0.99f * ((ex - 1.0f) * __builtin_amdgcn_rcpf(ex + 1.0f));
    float sxx = sx * sx, syy = sy * sy;
    float sxy = rho * sx * sy;
    float det = sxx * syy - sxy * sxy;               // >= 0.0199
    float inv_det = 1.0f / det;

    float a = -0.5f * syy * inv_det;
    float b =  sxy * inv_det;
    float c = -0.5f * sxx * inv_det;

    int i = tok % NTOK;
    float pack;
    if (i == 0) { a = 0.0f; b = 0.0f; c = 0.0f; pack = 0.0f; }
    else {
        int ip = i - 1;
        int ri = ip / 24;
        int ci = ip - ri * 24;
        pack = (float)(ri * 32 + ci);
    }
    coef[tok] = make_float4(a, b, c, pack);
}

// ---------------------------------------------------------------------------
// Kernel B v2: elementwise mask. rowmax(kernel)==1 structurally, so
// probs = clip(exp(w), eps, 1-eps). v2: both candidate coef rows hoisted as
// unconditional independent loads BEFORE u4 (3 loads in flight, no dependent
// load in the per-element chain), per-element select via cndmask.
// ---------------------------------------------------------------------------
__global__ __launch_bounds__(256) void mask_kernel(
    const float4* __restrict__ u4, const float4* __restrict__ coef,
    float4* __restrict__ out4)
{
    int vid = blockIdx.x * 256 + threadIdx.x;
    if (vid >= TOTAL_VEC) return;

    int e0 = vid * 4;
    unsigned row0 = (unsigned)e0 / 577u;             // magic-div
    int j0 = e0 - (int)row0 * 577;

    // at most one row crossing within 4 elems; row0+1 stays < BHN (last vec
    // has j0 = 573 -> no crossing), so the load below is always in-bounds.
    unsigned row1 = row0 + ((j0 + 3 >= 577) ? 1u : 0u);
    float4 cf0 = coef[row0];
    float4 cf1 = coef[row1];
    float4 uu = u4[vid];

    float um[4] = {uu.x, uu.y, uu.z, uu.w};
    float res[4];

    #pragma unroll
    for (int m = 0; m < 4; ++m) {
        int j = j0 + m;
        bool crossed = (j >= 577);
        if (crossed) j -= 577;
        float4 cf;
        cf.x = crossed ? cf1.x : cf0.x;
        cf.y = crossed ? cf1.y : cf0.y;
        cf.z = crossed ? cf1.z : cf0.z;
        cf.w = crossed ? cf1.w : cf0.w;
        int rc = (int)cf.w;

        float dx = 0.0f, dy = 0.0f;
        if (j > 0) {
            unsigned jj = (unsigned)(j - 1);
            unsigned rj = jj / 24u;                  // magic-div
            unsigned cj = jj - rj * 24u;
            dx = (float)((rc >> 5) - (int)rj);
            dy = (float)((rc & 31) - (int)cj);
        }

        // w = a*dx^2 + b*dx*dy + c*dy^2  (<= 0)
        float w = fmaf(fmaf(cf.x, dx, cf.y * dy), dx, cf.z * (dy * dy));

        float p = __expf(w);
        p = fminf(fmaxf(p, EPS_F), 1.0f - EPS_F);

        float uk  = um[m];
        float num = p * uk;                          // >= 1e-12
        float den = (1.0f - p) * (1.0f - uk);
        float t = 10.0f * (__logf(num) - __logf(den));   // (logits+noise)/TEMP

        res[m] = __builtin_amdgcn_rcpf(1.0f + __expf(-t));
    }

    out4[vid] = make_float4(res[0], res[1], res[2], res[3]);
}

// ---------------------------------------------------------------------------
extern "C" void kernel_launch(void* const* d_in, const int* in_sizes, int n_in,
                              void* d_out, int out_size, void* d_ws, size_t ws_size,
                              hipStream_t stream) {
    const float* q  = (const float*)d_in[0];
    const float* W1 = (const float*)d_in[1];
    const float* b1 = (const float*)d_in[2];
    const float* W2 = (const float*)d_in[3];
    const float* b2 = (const float*)d_in[4];
    const float* u  = (const float*)d_in[5];
    // d_in[6] = dists: recomputed on the fly, not loaded.

    float4* coef = (float4*)d_ws;                    // 886 KB scratch

    sigma_coef_kernel<<<(BHN + 255) / 256, 256, 0, stream>>>(q, W1, b1, W2, b2, coef);
    mask_kernel<<<(TOTAL_VEC + 255) / 256, 256, 0, stream>>>(
        (const float4*)u, coef, (float4*)d_out);
}